// Round 17
// baseline (2525.087 us; speedup 1.0000x reference)
//
#include <hip/hip_runtime.h>
#include <hip/hip_bf16.h>
#include <hip/hip_fp8.h>
#include <math.h>

#define H 32
#define SCB 1024
#define S 4   // dst-node slots per wave in k_gather (r11-proven)

__device__ __forceinline__ unsigned f2bf(float f) {  // f32 -> bf16 bits, RNE
  unsigned u = __float_as_uint(f);
  return (u + 0x7fffu + ((u >> 16) & 1u)) >> 16;
}
__device__ __forceinline__ float bflo(unsigned p) { return __uint_as_float(p << 16); }
__device__ __forceinline__ float bfhi(unsigned p) { return __uint_as_float(p & 0xffff0000u); }

// f32 -> OCP e4m3fn byte (RNE, saturating) — proven encode path
__device__ __forceinline__ unsigned f2q(float f) {
  __hip_fp8_e4m3 q(f);
  return (unsigned)q.__x;
}
// manual e4m3fn -> f32 (fallback only)
__device__ __forceinline__ float q2f(unsigned b) {
  unsigned s = (b >> 7) & 1u, e = (b >> 3) & 15u, m = b & 7u;
  float vn = __uint_as_float((s << 31) | ((e + 120u) << 23) | (m << 20));
  float vs = __uint_as_float((s << 31) | 0x3f800000u) * ((float)(int)m * (1.0f / 512.0f));
  return (e == 0u) ? vs : vn;
}

// decode channel pair (x,u) from a dword of packed fp8 {x0,u0,x1,u1} (proven)
template <bool HI>
__device__ __forceinline__ void cvt2(unsigned dw, float& x, float& u) {
#if __has_builtin(__builtin_amdgcn_cvt_pk_f32_fp8)
  typedef float f32x2 __attribute__((ext_vector_type(2)));
  f32x2 v = __builtin_amdgcn_cvt_pk_f32_fp8((int)dw, HI);
  x = v[0]; u = v[1];
#else
  unsigned b = HI ? (dw >> 16) : dw;
  x = q2f(b & 255u); u = q2f((b >> 8) & 255u);
#endif
}

// pack {fp8(x0),fp8(u0),fp8(x1),fp8(u1)} into one dword — f2q only (proven)
__device__ __forceinline__ unsigned pack4(float x0, float u0, float x1, float u1) {
  return f2q(x0) | (f2q(u0) << 8) | (f2q(x1) << 16) | (f2q(u1) << 24);
}

// h = x@Wn+bn ; pk halves: pkh[half][n][8 dwords] (32B rows, 16 channels each)
__global__ void k_encode(const float* __restrict__ x, const float* __restrict__ Wn,
                         const float* __restrict__ bn, const float* __restrict__ lnw0,
                         const float* __restrict__ lnb0, float* __restrict__ h,
                         unsigned* __restrict__ pk0, unsigned* __restrict__ pk1,
                         int n, int fnode) {
  __shared__ float sw[H * H];
  int tid = threadIdx.x;
  for (int i = tid; i < H * H; i += blockDim.x) sw[i] = lnw0[i];
  __syncthreads();
  int gid = blockIdx.x * blockDim.x + tid;
  int node = gid >> 5, c = gid & 31;
  if (node >= n) return;
  float acc = bn[c];
  for (int k = 0; k < fnode; ++k)
    acc = fmaf(x[node * fnode + k], Wn[k * H + c], acc);
  h[node * H + c] = acc;
  float t = lnb0[c];
#pragma unroll
  for (int k = 0; k < H; ++k)
    t = fmaf(__shfl(acc, k, 32), sw[k * H + c], t);
  unsigned w = f2q(acc) | (f2q(t - acc) << 8);
  unsigned dw = w | (__shfl_xor(w, 1, 32) << 16);
  if (!(c & 1)) {
    unsigned* ph = (c < 16) ? pk0 : pk1;
    ph[node * 8 + ((c & 15) >> 1)] = dw;
  }
}

// W2[l] = We @ le_w[l]  ([2,H]) ; b2[l] = be @ le_w[l] + le_b[l]
__global__ void k_fold(const float* __restrict__ We, const float* __restrict__ be,
                       const float* __restrict__ lew, const float* __restrict__ leb,
                       float* __restrict__ W2, float* __restrict__ b2, int L) {
  int gid = blockIdx.x * blockDim.x + threadIdx.x;
  if (gid >= L * H) return;
  int l = gid >> 5, c = gid & 31;
  const float* lw = lew + (size_t)l * H * H;
  float a0 = 0.f, a1 = 0.f, bb = leb[l * H + c];
  for (int j = 0; j < H; ++j) {
    float w = lw[j * H + c];
    a0 = fmaf(We[j], w, a0);
    a1 = fmaf(We[H + j], w, a1);
    bb = fmaf(be[j], w, bb);
  }
  W2[l * 2 * H + c] = a0;
  W2[l * 2 * H + H + c] = a1;
  b2[l * H + c] = bb;
}

__global__ void k_hist(const int* __restrict__ dst, unsigned* __restrict__ cnt, int e) {
  int i = blockIdx.x * blockDim.x + threadIdx.x;
  if (i < e) atomicAdd(&cnt[dst[i]], 1u);
}

__global__ void k_scan1(const unsigned* __restrict__ cnt, unsigned* __restrict__ out,
                        unsigned* __restrict__ bsum, int n) {
  __shared__ unsigned s[SCB];
  int i = blockIdx.x * SCB + threadIdx.x;
  unsigned v = (i < n) ? cnt[i] : 0u;
  s[threadIdx.x] = v;
  __syncthreads();
  for (int off = 1; off < SCB; off <<= 1) {
    unsigned u = (threadIdx.x >= off) ? s[threadIdx.x - off] : 0u;
    __syncthreads();
    s[threadIdx.x] += u;
    __syncthreads();
  }
  if (i < n) out[i] = s[threadIdx.x] - v;
  if (threadIdx.x == SCB - 1) bsum[blockIdx.x] = s[SCB - 1];
}

__global__ void k_scan2(const unsigned* __restrict__ bsum, unsigned* __restrict__ boff,
                        unsigned* __restrict__ total_out, int nb) {
  __shared__ unsigned s[SCB];
  unsigned v = ((int)threadIdx.x < nb) ? bsum[threadIdx.x] : 0u;
  s[threadIdx.x] = v;
  __syncthreads();
  for (int off = 1; off < SCB; off <<= 1) {
    unsigned u = (threadIdx.x >= off) ? s[threadIdx.x - off] : 0u;
    __syncthreads();
    s[threadIdx.x] += u;
    __syncthreads();
  }
  if ((int)threadIdx.x < nb) boff[threadIdx.x] = s[threadIdx.x] - v;
  if (threadIdx.x == SCB - 1) *total_out = s[SCB - 1];
}

__global__ void k_scan3(unsigned* __restrict__ row_ptr, const unsigned* __restrict__ boff,
                        unsigned* __restrict__ fill, int n) {
  int i = blockIdx.x * blockDim.x + threadIdx.x;
  if (i >= n) return;
  unsigned v = row_ptr[i] + boff[i >> 10];
  row_ptr[i] = v;
  fill[i] = v;
}

// rec = {src | (bf16 attr pair)<<32} as u64 (plain store — r11-proven path)
__global__ void k_scatter(const int* __restrict__ src, const int* __restrict__ dst,
                          const float* __restrict__ ea, unsigned* __restrict__ fill,
                          unsigned long long* __restrict__ recs, int e) {
  int i = blockIdx.x * blockDim.x + threadIdx.x;
  if (i >= e) return;
  int d = dst[i];
  unsigned pos = atomicAdd(&fill[d], 1u);
  float2 a = ((const float2*)ea)[i];
  recs[pos] = (unsigned long long)(unsigned)src[i] |
              ((unsigned long long)(f2bf(a.x) | (f2bf(a.y) << 16)) << 32);
}

// 4-channel edge accumulate from one uint2 (2 packed dwords)
__device__ __forceinline__ void edge_acc4(float (&acc)[4], uint2 pv, unsigned attr, float v,
                                          const float (&w0v)[4], const float (&w1v)[4],
                                          const float (&bbv)[4]) {
  float a0 = bflo(attr), a1 = bfhi(attr);
  unsigned dws[2] = {pv.x, pv.y};
#pragma unroll
  for (int d = 0; d < 2; ++d) {
    float x0, u0, x1, u1;
    cvt2<false>(dws[d], x0, u0);
    cvt2<true>(dws[d], x1, u1);
    float e0 = fmaf(a0, w0v[2 * d], fmaf(a1, w1v[2 * d], bbv[2 * d]));
    float e1 = fmaf(a0, w0v[2 * d + 1], fmaf(a1, w1v[2 * d + 1], bbv[2 * d + 1]));
    acc[2 * d]     = fmaf(v, fmaf(e0, u0, x0), acc[2 * d]);
    acc[2 * d + 1] = fmaf(v, fmaf(e1, u1, x1), acc[2 * d + 1]);
  }
}

// half-channel gather pass (r11 structure): S slots/wave, 16 edges/gather-instr
// (4 lanes x uint2 per 32B row). pkh half = 3.2MB -> per-XCD L2-resident;
// recs nt-loaded so the stream cannot evict pkh from L2.
__global__ void __launch_bounds__(256) k_gather(
    const unsigned* __restrict__ pkh, const unsigned* __restrict__ row_ptr,
    const unsigned long long* __restrict__ recs, const float* __restrict__ W2l,
    const float* __restrict__ b2l, int co, float* __restrict__ agg, int n, int e) {
  int tid = threadIdx.x;
  int lane = tid & 63;
  int wv = blockIdx.x * 4 + (tid >> 6);
  int n0 = wv * S;
  if (n0 >= n) return;
  int sub = lane & 3;
  unsigned eoff = (unsigned)(lane >> 2);
  float w0v[4], w1v[4], bbv[4];
#pragma unroll
  for (int j = 0; j < 4; ++j) {
    int ch = co + sub * 4 + j;
    w0v[j] = W2l[ch]; w1v[j] = W2l[H + ch]; bbv[j] = b2l[ch];
  }
  unsigned rp[S + 1];
#pragma unroll
  for (int i = 0; i <= S; ++i) {
    int idx = n0 + i;
    rp[i] = row_ptr[idx < n ? idx : n];
  }
  unsigned b0[S], b1[S], rr[S];
  unsigned R = 0;
#pragma unroll
  for (int s = 0; s < S; ++s) {
    b0[s] = rp[s]; b1[s] = rp[s + 1];
    rr[s] = (b1[s] - b0[s] + 15u) >> 4;
    R = rr[s] > R ? rr[s] : R;
  }
  float acc[S][4] = {};
  const uint2* pk2 = (const uint2*)pkh;
  unsigned emax = (unsigned)(e - 1);
  unsigned long long cur[S], nxt[S];
#pragma unroll
  for (int s = 0; s < S; ++s) {
    unsigned ix = b0[s] + eoff;
    unsigned cl = (ix < b1[s]) ? ix : b0[s];
    cl = cl < emax ? cl : emax;
    cur[s] = __builtin_nontemporal_load(&recs[cl]);
  }
  for (unsigned r = 0; r < R; ++r) {
    uint2 pv[S];
#pragma unroll
    for (int s = 0; s < S; ++s)
      if (r < rr[s]) pv[s] = pk2[(size_t)(unsigned)cur[s] * 4 + sub];
#pragma unroll
    for (int s = 0; s < S; ++s) {
      nxt[s] = cur[s];
      if (r + 1 < rr[s]) {
        unsigned ix = b0[s] + (r + 1) * 16u + eoff;
        unsigned cl = (ix < b1[s]) ? ix : b0[s];
        cl = cl < emax ? cl : emax;
        nxt[s] = __builtin_nontemporal_load(&recs[cl]);
      }
    }
    unsigned rb = r << 4;
#pragma unroll
    for (int s = 0; s < S; ++s)
      if (r < rr[s]) {
        float v = (b0[s] + rb + eoff < b1[s]) ? 1.f : 0.f;
        edge_acc4(acc[s], pv[s], (unsigned)(cur[s] >> 32), v, w0v, w1v, bbv);
      }
#pragma unroll
    for (int s = 0; s < S; ++s) cur[s] = nxt[s];
  }
#pragma unroll
  for (int s = 0; s < S; ++s)
#pragma unroll
    for (int j = 0; j < 4; ++j) {
      acc[s][j] += __shfl_xor(acc[s][j], 4, 64);
      acc[s][j] += __shfl_xor(acc[s][j], 8, 64);
      acc[s][j] += __shfl_xor(acc[s][j], 16, 64);
      acc[s][j] += __shfl_xor(acc[s][j], 32, 64);
    }
  if (lane < 4) {
#pragma unroll
    for (int s = 0; s < S; ++s) {
      if (n0 + s < n) {
        float4* o = (float4*)&agg[(size_t)(n0 + s) * H + co + lane * 4];
        o[0] = make_float4(acc[s][0], acc[s][1], acc[s][2], acc[s][3]);
      }
    }
  }
}

// node-per-lane update: o = relu([h,agg]@luw+lub); t = o@lnw+lnb; pk halves out.
__global__ void __launch_bounds__(256) k_update(
    const float* __restrict__ h, const float* __restrict__ agg,
    const float* __restrict__ luw, const float* __restrict__ lub,
    const float* __restrict__ lnw, const float* __restrict__ lnb,
    float* __restrict__ hout, unsigned* __restrict__ pk0,
    unsigned* __restrict__ pk1, int n) {
  int node = blockIdx.x * blockDim.x + threadIdx.x;
  if (node >= n) return;
  float hr[H], ar[H];
  const float4* h4 = (const float4*)(h + (size_t)node * H);
  const float4* a4 = (const float4*)(agg + (size_t)node * H);
#pragma unroll
  for (int q = 0; q < 8; ++q) {
    float4 v = h4[q];
    hr[4 * q] = v.x; hr[4 * q + 1] = v.y; hr[4 * q + 2] = v.z; hr[4 * q + 3] = v.w;
  }
#pragma unroll
  for (int q = 0; q < 8; ++q) {
    float4 v = a4[q];
    ar[4 * q] = v.x; ar[4 * q + 1] = v.y; ar[4 * q + 2] = v.z; ar[4 * q + 3] = v.w;
  }
  float o[H];
#pragma unroll
  for (int c = 0; c < H; ++c) o[c] = lub[c];
#pragma unroll
  for (int k = 0; k < H; ++k)
#pragma unroll
    for (int c = 0; c < H; ++c)
      o[c] = fmaf(hr[k], luw[k * H + c], o[c]);
#pragma unroll
  for (int k = 0; k < H; ++k)
#pragma unroll
    for (int c = 0; c < H; ++c)
      o[c] = fmaf(ar[k], luw[(H + k) * H + c], o[c]);
#pragma unroll
  for (int c = 0; c < H; ++c) o[c] = fmaxf(o[c], 0.f);
  float4* ho = (float4*)(hout + (size_t)node * H);
#pragma unroll
  for (int q = 0; q < 8; ++q)
    ho[q] = make_float4(o[4 * q], o[4 * q + 1], o[4 * q + 2], o[4 * q + 3]);
  if (pk0) {
    float t[H];
#pragma unroll
    for (int c = 0; c < H; ++c) t[c] = lnb[c];
#pragma unroll
    for (int k = 0; k < H; ++k)
#pragma unroll
      for (int c = 0; c < H; ++c)
        t[c] = fmaf(o[k], lnw[k * H + c], t[c]);
    unsigned dws[16];
#pragma unroll
    for (int d = 0; d < 16; ++d)
      dws[d] = pack4(o[2 * d], t[2 * d] - o[2 * d],
                     o[2 * d + 1], t[2 * d + 1] - o[2 * d + 1]);
    uint4* p0 = (uint4*)(pk0 + (size_t)node * 8);
    p0[0] = make_uint4(dws[0], dws[1], dws[2], dws[3]);
    p0[1] = make_uint4(dws[4], dws[5], dws[6], dws[7]);
    uint4* p1 = (uint4*)(pk1 + (size_t)node * 8);
    p1[0] = make_uint4(dws[8], dws[9], dws[10], dws[11]);
    p1[1] = make_uint4(dws[12], dws[13], dws[14], dws[15]);
  }
}

// classifier: sigmoid(relu(h@c1+b1)@c2 + b2)
__global__ void k_cls(const float* __restrict__ h, const float* __restrict__ c1w,
                      const float* __restrict__ c1b, const float* __restrict__ c2w,
                      const float* __restrict__ c2b, float* __restrict__ out, int n) {
  __shared__ float sw[H * H];
  int tid = threadIdx.x;
  for (int i = tid; i < H * H; i += blockDim.x) sw[i] = c1w[i];
  __syncthreads();
  int gid = blockIdx.x * blockDim.x + tid;
  int node = gid >> 5, c = gid & 31;
  if (node >= n) return;
  float hv = h[node * H + c];
  float z = c1b[c];
#pragma unroll
  for (int k = 0; k < H; ++k)
    z = fmaf(__shfl(hv, k, 32), sw[k * H + c], z);
  z = fmaxf(z, 0.f);
  float r = z * c2w[c];
#pragma unroll
  for (int m = 16; m >= 1; m >>= 1)
    r += __shfl_xor(r, m, 32);
  if (c == 0) out[node] = 1.f / (1.f + expf(-(r + c2b[0])));
}

extern "C" void kernel_launch(void* const* d_in, const int* in_sizes, int n_in,
                              void* d_out, int out_size, void* d_ws, size_t ws_size,
                              hipStream_t stream) {
  const float* x         = (const float*)d_in[0];
  const float* edge_attr = (const float*)d_in[1];
  const int*   edge_index= (const int*)d_in[2];
  const float* Wn        = (const float*)d_in[3];
  const float* bn        = (const float*)d_in[4];
  const float* We        = (const float*)d_in[5];
  const float* be        = (const float*)d_in[6];
  const float* ln_w      = (const float*)d_in[7];
  const float* ln_b      = (const float*)d_in[8];
  const float* le_w      = (const float*)d_in[9];
  const float* le_b      = (const float*)d_in[10];
  const float* lu_w      = (const float*)d_in[11];
  const float* lu_b      = (const float*)d_in[12];
  const float* c1w       = (const float*)d_in[13];
  const float* c1b       = (const float*)d_in[14];
  const float* c2w       = (const float*)d_in[15];
  const float* c2b       = (const float*)d_in[16];

  const int N_ = in_sizes[0] / 5;
  const int E_ = in_sizes[1] / 2;
  const int L_ = in_sizes[7] / (H * H);
  const int* src = edge_index;
  const int* dst = edge_index + E_;

  char* ws = (char*)d_ws;
  size_t off = 0;
  auto alloc = [&](size_t bytes) -> void* {
    void* p = ws + off;
    off = (off + bytes + 255) & ~(size_t)255;
    return p;
  };
  float*              hA      = (float*)alloc((size_t)N_ * H * 4);
  float*              hB      = (float*)alloc((size_t)N_ * H * 4);
  unsigned*           pkA0    = (unsigned*)alloc((size_t)N_ * 8 * 4);
  unsigned*           pkA1    = (unsigned*)alloc((size_t)N_ * 8 * 4);
  unsigned*           pkB0    = (unsigned*)alloc((size_t)N_ * 8 * 4);
  unsigned*           pkB1    = (unsigned*)alloc((size_t)N_ * 8 * 4);
  float*              agg     = (float*)alloc((size_t)N_ * H * 4);
  unsigned*           row_ptr = (unsigned*)alloc((size_t)(N_ + 1) * 4);
  unsigned*           fill    = (unsigned*)alloc((size_t)N_ * 4);
  unsigned long long* recs    = (unsigned long long*)alloc((size_t)E_ * 8);
  float*              W2      = (float*)alloc((size_t)L_ * 2 * H * 4);
  float*              b2      = (float*)alloc((size_t)L_ * H * 4);
  unsigned*           bsum    = (unsigned*)alloc((size_t)SCB * 4);
  unsigned*           boff    = (unsigned*)alloc((size_t)SCB * 4);

  const int tb = 256;
  const int nb = (N_ + SCB - 1) / SCB;
  hipMemsetAsync(fill, 0, (size_t)N_ * 4, stream);
  k_encode<<<(N_ * 32 + tb - 1) / tb, tb, 0, stream>>>(x, Wn, bn, ln_w, ln_b, hA, pkA0, pkA1, N_, 5);
  k_fold<<<(L_ * H + 63) / 64, 64, 0, stream>>>(We, be, le_w, le_b, W2, b2, L_);
  k_hist<<<(E_ + tb - 1) / tb, tb, 0, stream>>>(dst, fill, E_);
  k_scan1<<<nb, SCB, 0, stream>>>(fill, row_ptr, bsum, N_);
  k_scan2<<<1, SCB, 0, stream>>>(bsum, boff, row_ptr + N_, nb);
  k_scan3<<<(N_ + tb - 1) / tb, tb, 0, stream>>>(row_ptr, boff, fill, N_);
  k_scatter<<<(E_ + tb - 1) / tb, tb, 0, stream>>>(src, dst, edge_attr, fill, recs, E_);

  float* hc = hA;  float* hn = hB;
  unsigned* pc0 = pkA0; unsigned* pc1 = pkA1;
  unsigned* pn0 = pkB0; unsigned* pn1 = pkB1;
  const int gblocks = (N_ + 4 * S - 1) / (4 * S);
  for (int l = 0; l < L_; ++l) {
    bool last = (l == L_ - 1);
    const float* w2l = W2 + l * 2 * H;
    const float* b2l = b2 + l * H;
    k_gather<<<gblocks, 256, 0, stream>>>(pc0, row_ptr, recs, w2l, b2l, 0, agg, N_, E_);
    k_gather<<<gblocks, 256, 0, stream>>>(pc1, row_ptr, recs, w2l, b2l, 16, agg, N_, E_);
    k_update<<<(N_ + tb - 1) / tb, tb, 0, stream>>>(
        hc, agg, lu_w + (size_t)l * 2 * H * H, lu_b + (size_t)l * H,
        last ? nullptr : ln_w + (size_t)(l + 1) * H * H,
        last ? nullptr : ln_b + (size_t)(l + 1) * H,
        hn, last ? nullptr : pn0, last ? nullptr : pn1, N_);
    float* tf = hc; hc = hn; hn = tf;
    unsigned* t0 = pc0; pc0 = pn0; pn0 = t0;
    unsigned* t1 = pc1; pc1 = pn1; pn1 = t1;
  }
  k_cls<<<(N_ * 32 + tb - 1) / tb, tb, 0, stream>>>(hc, c1w, c1b, c2w, c2b, (float*)d_out, N_);
}

// Round 18
// 1924.925 us; speedup vs baseline: 1.3118x; 1.3118x over previous
//
#include <hip/hip_runtime.h>
#include <hip/hip_bf16.h>
#include <hip/hip_fp8.h>
#include <math.h>

#define H 32
#define SCB 1024

__device__ __forceinline__ unsigned f2bf(float f) {  // f32 -> bf16 bits, RNE
  unsigned u = __float_as_uint(f);
  return (u + 0x7fffu + ((u >> 16) & 1u)) >> 16;
}
__device__ __forceinline__ float bflo(unsigned p) { return __uint_as_float(p << 16); }
__device__ __forceinline__ float bfhi(unsigned p) { return __uint_as_float(p & 0xffff0000u); }

// f32 -> OCP e4m3fn byte (RNE, saturating) — proven encode path
__device__ __forceinline__ unsigned f2q(float f) {
  __hip_fp8_e4m3 q(f);
  return (unsigned)q.__x;
}
// manual e4m3fn -> f32 (fallback only)
__device__ __forceinline__ float q2f(unsigned b) {
  unsigned s = (b >> 7) & 1u, e = (b >> 3) & 15u, m = b & 7u;
  float vn = __uint_as_float((s << 31) | ((e + 120u) << 23) | (m << 20));
  float vs = __uint_as_float((s << 31) | 0x3f800000u) * ((float)(int)m * (1.0f / 512.0f));
  return (e == 0u) ? vs : vn;
}

// decode channel pair (x,u) from a dword of packed fp8 {x0,u0,x1,u1} (proven)
template <bool HI>
__device__ __forceinline__ void cvt2(unsigned dw, float& x, float& u) {
#if __has_builtin(__builtin_amdgcn_cvt_pk_f32_fp8)
  typedef float f32x2 __attribute__((ext_vector_type(2)));
  f32x2 v = __builtin_amdgcn_cvt_pk_f32_fp8((int)dw, HI);
  x = v[0]; u = v[1];
#else
  unsigned b = HI ? (dw >> 16) : dw;
  x = q2f(b & 255u); u = q2f((b >> 8) & 255u);
#endif
}

// pack {fp8(x0),fp8(u0),fp8(x1),fp8(u1)} into one dword — f2q only (proven)
__device__ __forceinline__ unsigned pack4(float x0, float u0, float x1, float u1) {
  return f2q(x0) | (f2q(u0) << 8) | (f2q(x1) << 16) | (f2q(u1) << 24);
}

// h = x@Wn+bn ; pk[n][16 dwords]: dword d = {x(2d),u(2d),x(2d+1),u(2d+1)} fp8
__global__ void k_encode(const float* __restrict__ x, const float* __restrict__ Wn,
                         const float* __restrict__ bn, const float* __restrict__ lnw0,
                         const float* __restrict__ lnb0, float* __restrict__ h,
                         unsigned* __restrict__ pk, int n, int fnode) {
  __shared__ float sw[H * H];
  int tid = threadIdx.x;
  for (int i = tid; i < H * H; i += blockDim.x) sw[i] = lnw0[i];
  __syncthreads();
  int gid = blockIdx.x * blockDim.x + tid;
  int node = gid >> 5, c = gid & 31;
  if (node >= n) return;
  float acc = bn[c];
  for (int k = 0; k < fnode; ++k)
    acc = fmaf(x[node * fnode + k], Wn[k * H + c], acc);
  h[node * H + c] = acc;
  float t = lnb0[c];
#pragma unroll
  for (int k = 0; k < H; ++k)
    t = fmaf(__shfl(acc, k, 32), sw[k * H + c], t);
  unsigned w = f2q(acc) | (f2q(t - acc) << 8);
  unsigned dw = w | (__shfl_xor(w, 1, 32) << 16);
  if (!(c & 1)) pk[node * 16 + (c >> 1)] = dw;
}

// W2[l] = We @ le_w[l]  ([2,H]) ; b2[l] = be @ le_w[l] + le_b[l]
__global__ void k_fold(const float* __restrict__ We, const float* __restrict__ be,
                       const float* __restrict__ lew, const float* __restrict__ leb,
                       float* __restrict__ W2, float* __restrict__ b2, int L) {
  int gid = blockIdx.x * blockDim.x + threadIdx.x;
  if (gid >= L * H) return;
  int l = gid >> 5, c = gid & 31;
  const float* lw = lew + (size_t)l * H * H;
  float a0 = 0.f, a1 = 0.f, bb = leb[l * H + c];
  for (int j = 0; j < H; ++j) {
    float w = lw[j * H + c];
    a0 = fmaf(We[j], w, a0);
    a1 = fmaf(We[H + j], w, a1);
    bb = fmaf(be[j], w, bb);
  }
  W2[l * 2 * H + c] = a0;
  W2[l * 2 * H + H + c] = a1;
  b2[l * H + c] = bb;
}

__global__ void k_hist(const int* __restrict__ dst, unsigned* __restrict__ cnt, int e) {
  int i = blockIdx.x * blockDim.x + threadIdx.x;
  if (i < e) atomicAdd(&cnt[dst[i]], 1u);
}

__global__ void k_scan1(const unsigned* __restrict__ cnt, unsigned* __restrict__ out,
                        unsigned* __restrict__ bsum, int n) {
  __shared__ unsigned s[SCB];
  int i = blockIdx.x * SCB + threadIdx.x;
  unsigned v = (i < n) ? cnt[i] : 0u;
  s[threadIdx.x] = v;
  __syncthreads();
  for (int off = 1; off < SCB; off <<= 1) {
    unsigned u = (threadIdx.x >= off) ? s[threadIdx.x - off] : 0u;
    __syncthreads();
    s[threadIdx.x] += u;
    __syncthreads();
  }
  if (i < n) out[i] = s[threadIdx.x] - v;
  if (threadIdx.x == SCB - 1) bsum[blockIdx.x] = s[SCB - 1];
}

__global__ void k_scan2(const unsigned* __restrict__ bsum, unsigned* __restrict__ boff,
                        unsigned* __restrict__ total_out, int nb) {
  __shared__ unsigned s[SCB];
  unsigned v = ((int)threadIdx.x < nb) ? bsum[threadIdx.x] : 0u;
  s[threadIdx.x] = v;
  __syncthreads();
  for (int off = 1; off < SCB; off <<= 1) {
    unsigned u = (threadIdx.x >= off) ? s[threadIdx.x - off] : 0u;
    __syncthreads();
    s[threadIdx.x] += u;
    __syncthreads();
  }
  if ((int)threadIdx.x < nb) boff[threadIdx.x] = s[threadIdx.x] - v;
  if (threadIdx.x == SCB - 1) *total_out = s[SCB - 1];
}

__global__ void k_scan3(unsigned* __restrict__ row_ptr, const unsigned* __restrict__ boff,
                        unsigned* __restrict__ fill, int n) {
  int i = blockIdx.x * blockDim.x + threadIdx.x;
  if (i >= n) return;
  unsigned v = row_ptr[i] + boff[i >> 10];
  row_ptr[i] = v;
  fill[i] = v;
}

// rec = {src, bf16(attr0) | bf16(attr1)<<16}
__global__ void k_scatter(const int* __restrict__ src, const int* __restrict__ dst,
                          const float* __restrict__ ea, unsigned* __restrict__ fill,
                          uint2* __restrict__ recs, int e) {
  int i = blockIdx.x * blockDim.x + threadIdx.x;
  if (i >= e) return;
  int d = dst[i];
  unsigned pos = atomicAdd(&fill[d], 1u);
  float2 a = ((const float2*)ea)[i];
  recs[pos] = make_uint2((unsigned)src[i], f2bf(a.x) | (f2bf(a.y) << 16));
}

__device__ __forceinline__ void edge_acc(float (&acc)[8], uint4 pv, uint2 rec, float v,
                                         const float (&w0v)[8], const float (&w1v)[8],
                                         const float (&bbv)[8]) {
  float a0 = bflo(rec.y), a1 = bfhi(rec.y);
  unsigned dws[4] = {pv.x, pv.y, pv.z, pv.w};
#pragma unroll
  for (int d = 0; d < 4; ++d) {
    float x0, u0, x1, u1;
    cvt2<false>(dws[d], x0, u0);
    cvt2<true>(dws[d], x1, u1);
    float e0 = fmaf(a0, w0v[2 * d], fmaf(a1, w1v[2 * d], bbv[2 * d]));
    float e1 = fmaf(a0, w0v[2 * d + 1], fmaf(a1, w1v[2 * d + 1], bbv[2 * d + 1]));
    acc[2 * d]     = fmaf(v, fmaf(e0, u0, x0), acc[2 * d]);
    acc[2 * d + 1] = fmaf(v, fmaf(e1, u1, x1), acc[2 * d + 1]);
  }
}

// gather-only: one wave = 4 interleaved dst nodes (breadth for memory concurrency).
// Per round: 4 independent pk gathers (16 edges each) + 4 rec prefetches in flight.
__global__ void __launch_bounds__(256) k_gather(
    const unsigned* __restrict__ pk, const unsigned* __restrict__ row_ptr,
    const uint2* __restrict__ recs, const float* __restrict__ W2l,
    const float* __restrict__ b2l, float* __restrict__ agg, int n, int e) {
  int tid = threadIdx.x;
  int lane = tid & 63;
  int gw = blockIdx.x * 4 + (tid >> 6);
  int n0 = gw * 4;
  if (n0 >= n) return;
  int sub = lane & 3;
  unsigned eoff = (unsigned)(lane >> 2);
  float w0v[8], w1v[8], bbv[8];
#pragma unroll
  for (int j = 0; j < 8; ++j) {
    int ch = sub * 8 + j;
    w0v[j] = W2l[ch]; w1v[j] = W2l[H + ch]; bbv[j] = b2l[ch];
  }
  unsigned rp[5];
#pragma unroll
  for (int i = 0; i < 5; ++i) {
    int idx = n0 + i;
    rp[i] = row_ptr[idx < n ? idx : n];
  }
  unsigned b0_0 = rp[0], b1_0 = rp[1];
  unsigned b0_1 = rp[1], b1_1 = rp[2];
  unsigned b0_2 = rp[2], b1_2 = rp[3];
  unsigned b0_3 = rp[3], b1_3 = rp[4];
  unsigned r_0 = (b1_0 - b0_0 + 15u) >> 4;
  unsigned r_1 = (b1_1 - b0_1 + 15u) >> 4;
  unsigned r_2 = (b1_2 - b0_2 + 15u) >> 4;
  unsigned r_3 = (b1_3 - b0_3 + 15u) >> 4;
  unsigned R = r_0;
  R = r_1 > R ? r_1 : R;
  R = r_2 > R ? r_2 : R;
  R = r_3 > R ? r_3 : R;
  float acc0[8] = {0,0,0,0,0,0,0,0};
  float acc1[8] = {0,0,0,0,0,0,0,0};
  float acc2[8] = {0,0,0,0,0,0,0,0};
  float acc3[8] = {0,0,0,0,0,0,0,0};
  const uint4* pk4 = (const uint4*)pk;
  unsigned emax = (unsigned)(e - 1);

  // prologue: load round-0 recs for all 4 nodes
  uint2 c_0, c_1, c_2, c_3;
  {
    unsigned ix, cl;
    ix = b0_0 + eoff; cl = (ix < b1_0) ? ix : b0_0; c_0 = recs[cl < emax ? cl : emax];
    ix = b0_1 + eoff; cl = (ix < b1_1) ? ix : b0_1; c_1 = recs[cl < emax ? cl : emax];
    ix = b0_2 + eoff; cl = (ix < b1_2) ? ix : b0_2; c_2 = recs[cl < emax ? cl : emax];
    ix = b0_3 + eoff; cl = (ix < b1_3) ? ix : b0_3; c_3 = recs[cl < emax ? cl : emax];
  }
  for (unsigned r = 0; r < R; ++r) {
    bool h0 = r < r_0, h1 = r < r_1, h2 = r < r_2, h3 = r < r_3;
    // issue all pk gathers back-to-back (independent)
    uint4 p_0, p_1, p_2, p_3;
    if (h0) p_0 = pk4[(size_t)c_0.x * 4 + sub];
    if (h1) p_1 = pk4[(size_t)c_1.x * 4 + sub];
    if (h2) p_2 = pk4[(size_t)c_2.x * 4 + sub];
    if (h3) p_3 = pk4[(size_t)c_3.x * 4 + sub];
    // prefetch next-round recs
    uint2 n_0 = c_0, n_1 = c_1, n_2 = c_2, n_3 = c_3;
    {
      unsigned ix, cl;
      if (r + 1 < r_0) { ix = b0_0 + (r + 1) * 16u + eoff; cl = (ix < b1_0) ? ix : b0_0; n_0 = recs[cl < emax ? cl : emax]; }
      if (r + 1 < r_1) { ix = b0_1 + (r + 1) * 16u + eoff; cl = (ix < b1_1) ? ix : b0_1; n_1 = recs[cl < emax ? cl : emax]; }
      if (r + 1 < r_2) { ix = b0_2 + (r + 1) * 16u + eoff; cl = (ix < b1_2) ? ix : b0_2; n_2 = recs[cl < emax ? cl : emax]; }
      if (r + 1 < r_3) { ix = b0_3 + (r + 1) * 16u + eoff; cl = (ix < b1_3) ? ix : b0_3; n_3 = recs[cl < emax ? cl : emax]; }
    }
    // compute (validity recomputed from scalars)
    unsigned rb = r << 4;
    if (h0) { float v = (b0_0 + rb + eoff < b1_0) ? 1.f : 0.f; edge_acc(acc0, p_0, c_0, v, w0v, w1v, bbv); }
    if (h1) { float v = (b0_1 + rb + eoff < b1_1) ? 1.f : 0.f; edge_acc(acc1, p_1, c_1, v, w0v, w1v, bbv); }
    if (h2) { float v = (b0_2 + rb + eoff < b1_2) ? 1.f : 0.f; edge_acc(acc2, p_2, c_2, v, w0v, w1v, bbv); }
    if (h3) { float v = (b0_3 + rb + eoff < b1_3) ? 1.f : 0.f; edge_acc(acc3, p_3, c_3, v, w0v, w1v, bbv); }
    c_0 = n_0; c_1 = n_1; c_2 = n_2; c_3 = n_3;
  }
#pragma unroll
  for (int j = 0; j < 8; ++j) {
    acc0[j] += __shfl_xor(acc0[j], 4, 64);
    acc0[j] += __shfl_xor(acc0[j], 8, 64);
    acc0[j] += __shfl_xor(acc0[j], 16, 64);
    acc0[j] += __shfl_xor(acc0[j], 32, 64);
    acc1[j] += __shfl_xor(acc1[j], 4, 64);
    acc1[j] += __shfl_xor(acc1[j], 8, 64);
    acc1[j] += __shfl_xor(acc1[j], 16, 64);
    acc1[j] += __shfl_xor(acc1[j], 32, 64);
    acc2[j] += __shfl_xor(acc2[j], 4, 64);
    acc2[j] += __shfl_xor(acc2[j], 8, 64);
    acc2[j] += __shfl_xor(acc2[j], 16, 64);
    acc2[j] += __shfl_xor(acc2[j], 32, 64);
    acc3[j] += __shfl_xor(acc3[j], 4, 64);
    acc3[j] += __shfl_xor(acc3[j], 8, 64);
    acc3[j] += __shfl_xor(acc3[j], 16, 64);
    acc3[j] += __shfl_xor(acc3[j], 32, 64);
  }
  if (lane < 4) {
    float4* o;
    if (n0 < n) {
      o = (float4*)&agg[(size_t)n0 * H + lane * 8];
      o[0] = make_float4(acc0[0], acc0[1], acc0[2], acc0[3]);
      o[1] = make_float4(acc0[4], acc0[5], acc0[6], acc0[7]);
    }
    if (n0 + 1 < n) {
      o = (float4*)&agg[(size_t)(n0 + 1) * H + lane * 8];
      o[0] = make_float4(acc1[0], acc1[1], acc1[2], acc1[3]);
      o[1] = make_float4(acc1[4], acc1[5], acc1[6], acc1[7]);
    }
    if (n0 + 2 < n) {
      o = (float4*)&agg[(size_t)(n0 + 2) * H + lane * 8];
      o[0] = make_float4(acc2[0], acc2[1], acc2[2], acc2[3]);
      o[1] = make_float4(acc2[4], acc2[5], acc2[6], acc2[7]);
    }
    if (n0 + 3 < n) {
      o = (float4*)&agg[(size_t)(n0 + 3) * H + lane * 8];
      o[0] = make_float4(acc3[0], acc3[1], acc3[2], acc3[3]);
      o[1] = make_float4(acc3[4], acc3[5], acc3[6], acc3[7]);
    }
  }
}

// node-per-lane update: o = relu([h,agg]@luw+lub); t = o@lnw+lnb; pk = fp8 pack.
__global__ void __launch_bounds__(256) k_update(
    const float* __restrict__ h, const float* __restrict__ agg,
    const float* __restrict__ luw, const float* __restrict__ lub,
    const float* __restrict__ lnw, const float* __restrict__ lnb,
    float* __restrict__ hout, unsigned* __restrict__ pkout, int n) {
  int node = blockIdx.x * blockDim.x + threadIdx.x;
  if (node >= n) return;
  float hr[H], ar[H];
  const float4* h4 = (const float4*)(h + (size_t)node * H);
  const float4* a4 = (const float4*)(agg + (size_t)node * H);
#pragma unroll
  for (int q = 0; q < 8; ++q) {
    float4 v = h4[q];
    hr[4 * q] = v.x; hr[4 * q + 1] = v.y; hr[4 * q + 2] = v.z; hr[4 * q + 3] = v.w;
  }
#pragma unroll
  for (int q = 0; q < 8; ++q) {
    float4 v = a4[q];
    ar[4 * q] = v.x; ar[4 * q + 1] = v.y; ar[4 * q + 2] = v.z; ar[4 * q + 3] = v.w;
  }
  float o[H];
#pragma unroll
  for (int c = 0; c < H; ++c) o[c] = lub[c];
#pragma unroll
  for (int k = 0; k < H; ++k)
#pragma unroll
    for (int c = 0; c < H; ++c)
      o[c] = fmaf(hr[k], luw[k * H + c], o[c]);
#pragma unroll
  for (int k = 0; k < H; ++k)
#pragma unroll
    for (int c = 0; c < H; ++c)
      o[c] = fmaf(ar[k], luw[(H + k) * H + c], o[c]);
#pragma unroll
  for (int c = 0; c < H; ++c) o[c] = fmaxf(o[c], 0.f);
  float4* ho = (float4*)(hout + (size_t)node * H);
#pragma unroll
  for (int q = 0; q < 8; ++q)
    ho[q] = make_float4(o[4 * q], o[4 * q + 1], o[4 * q + 2], o[4 * q + 3]);
  if (pkout) {
    float t[H];
#pragma unroll
    for (int c = 0; c < H; ++c) t[c] = lnb[c];
#pragma unroll
    for (int k = 0; k < H; ++k)
#pragma unroll
      for (int c = 0; c < H; ++c)
        t[c] = fmaf(o[k], lnw[k * H + c], t[c]);
    unsigned dws[16];
#pragma unroll
    for (int d = 0; d < 16; ++d)
      dws[d] = pack4(o[2 * d], t[2 * d] - o[2 * d],
                     o[2 * d + 1], t[2 * d + 1] - o[2 * d + 1]);
    uint4* po = (uint4*)(pkout + (size_t)node * 16);
#pragma unroll
    for (int q = 0; q < 4; ++q)
      po[q] = make_uint4(dws[4 * q], dws[4 * q + 1], dws[4 * q + 2], dws[4 * q + 3]);
  }
}

// classifier: sigmoid(relu(h@c1+b1)@c2 + b2)
__global__ void k_cls(const float* __restrict__ h, const float* __restrict__ c1w,
                      const float* __restrict__ c1b, const float* __restrict__ c2w,
                      const float* __restrict__ c2b, float* __restrict__ out, int n) {
  __shared__ float sw[H * H];
  int tid = threadIdx.x;
  for (int i = tid; i < H * H; i += blockDim.x) sw[i] = c1w[i];
  __syncthreads();
  int gid = blockIdx.x * blockDim.x + tid;
  int node = gid >> 5, c = gid & 31;
  if (node >= n) return;
  float hv = h[node * H + c];
  float z = c1b[c];
#pragma unroll
  for (int k = 0; k < H; ++k)
    z = fmaf(__shfl(hv, k, 32), sw[k * H + c], z);
  z = fmaxf(z, 0.f);
  float r = z * c2w[c];
#pragma unroll
  for (int m = 16; m >= 1; m >>= 1)
    r += __shfl_xor(r, m, 32);
  if (c == 0) out[node] = 1.f / (1.f + expf(-(r + c2b[0])));
}

extern "C" void kernel_launch(void* const* d_in, const int* in_sizes, int n_in,
                              void* d_out, int out_size, void* d_ws, size_t ws_size,
                              hipStream_t stream) {
  const float* x         = (const float*)d_in[0];
  const float* edge_attr = (const float*)d_in[1];
  const int*   edge_index= (const int*)d_in[2];
  const float* Wn        = (const float*)d_in[3];
  const float* bn        = (const float*)d_in[4];
  const float* We        = (const float*)d_in[5];
  const float* be        = (const float*)d_in[6];
  const float* ln_w      = (const float*)d_in[7];
  const float* ln_b      = (const float*)d_in[8];
  const float* le_w      = (const float*)d_in[9];
  const float* le_b      = (const float*)d_in[10];
  const float* lu_w      = (const float*)d_in[11];
  const float* lu_b      = (const float*)d_in[12];
  const float* c1w       = (const float*)d_in[13];
  const float* c1b       = (const float*)d_in[14];
  const float* c2w       = (const float*)d_in[15];
  const float* c2b       = (const float*)d_in[16];

  const int N_ = in_sizes[0] / 5;
  const int E_ = in_sizes[1] / 2;
  const int L_ = in_sizes[7] / (H * H);
  const int* src = edge_index;
  const int* dst = edge_index + E_;

  char* ws = (char*)d_ws;
  size_t off = 0;
  auto alloc = [&](size_t bytes) -> void* {
    void* p = ws + off;
    off = (off + bytes + 255) & ~(size_t)255;
    return p;
  };
  float*    hA      = (float*)alloc((size_t)N_ * H * 4);
  float*    hB      = (float*)alloc((size_t)N_ * H * 4);
  unsigned* pkA     = (unsigned*)alloc((size_t)N_ * 16 * 4);
  unsigned* pkB     = (unsigned*)alloc((size_t)N_ * 16 * 4);
  float*    agg     = (float*)alloc((size_t)N_ * H * 4);
  unsigned* row_ptr = (unsigned*)alloc((size_t)(N_ + 1) * 4);
  unsigned* fill    = (unsigned*)alloc((size_t)N_ * 4);
  uint2*    recs    = (uint2*)alloc((size_t)E_ * 8);
  float*    W2      = (float*)alloc((size_t)L_ * 2 * H * 4);
  float*    b2      = (float*)alloc((size_t)L_ * H * 4);
  unsigned* bsum    = (unsigned*)alloc((size_t)SCB * 4);
  unsigned* boff    = (unsigned*)alloc((size_t)SCB * 4);

  const int tb = 256;
  const int nb = (N_ + SCB - 1) / SCB;
  hipMemsetAsync(fill, 0, (size_t)N_ * 4, stream);
  k_encode<<<(N_ * 32 + tb - 1) / tb, tb, 0, stream>>>(x, Wn, bn, ln_w, ln_b, hA, pkA, N_, 5);
  k_fold<<<(L_ * H + 63) / 64, 64, 0, stream>>>(We, be, le_w, le_b, W2, b2, L_);
  k_hist<<<(E_ + tb - 1) / tb, tb, 0, stream>>>(dst, fill, E_);
  k_scan1<<<nb, SCB, 0, stream>>>(fill, row_ptr, bsum, N_);
  k_scan2<<<1, SCB, 0, stream>>>(bsum, boff, row_ptr + N_, nb);
  k_scan3<<<(N_ + tb - 1) / tb, tb, 0, stream>>>(row_ptr, boff, fill, N_);
  k_scatter<<<(E_ + tb - 1) / tb, tb, 0, stream>>>(src, dst, edge_attr, fill, recs, E_);

  float* hc = hA;  float* hn = hB;
  unsigned* pc = pkA; unsigned* pn = pkB;
  for (int l = 0; l < L_; ++l) {
    bool last = (l == L_ - 1);
    k_gather<<<(N_ + 15) / 16, 256, 0, stream>>>(
        pc, row_ptr, recs, W2 + l * 2 * H, b2 + l * H, agg, N_, E_);
    k_update<<<(N_ + tb - 1) / tb, tb, 0, stream>>>(
        hc, agg, lu_w + (size_t)l * 2 * H * H, lu_b + (size_t)l * H,
        last ? nullptr : ln_w + (size_t)(l + 1) * H * H,
        last ? nullptr : ln_b + (size_t)(l + 1) * H,
        hn, last ? nullptr : pn, N_);
    float* tf = hc; hc = hn; hn = tf;
    unsigned* tp = pc; pc = pn; pn = tp;
  }
  k_cls<<<(N_ * 32 + tb - 1) / tb, tb, 0, stream>>>(hc, c1w, c1b, c2w, c2b, (float*)d_out, N_);
}